// Round 11
// baseline (713.716 us; speedup 1.0000x reference)
//
#include <hip/hip_runtime.h>

// Problem constants (fixed by the reference).
#define NN 100000
#define EE 1600000
// D_IN=64, H=128, E_IN=64, C=8
constexpr float BN_EPS = 1e-5f;

typedef __attribute__((ext_vector_type(8))) short short8;
typedef __attribute__((ext_vector_type(4))) float f32x4;

__device__ __forceinline__ short f2bf(float f) {  // RNE f32 -> bf16
    unsigned u = __float_as_uint(f);
    u += 0x7fff + ((u >> 16) & 1);
    return (short)(u >> 16);
}
__device__ __forceinline__ float bf2f(short s) {
    return __uint_as_float(((unsigned)(unsigned short)s) << 16);
}

// async global->LDS DMA, 16 B per lane. LDS dest must be base + lane*16
// within each wave (guaranteed by construction at all call sites).
typedef __attribute__((address_space(1))) const unsigned int guint;
typedef __attribute__((address_space(3))) unsigned int luint;
__device__ __forceinline__ void gload_lds16(const void* g, void* l) {
    __builtin_amdgcn_global_load_lds((guint*)g, (luint*)l, 16, 0, 0);
}

// ---------------------------------------------------------------------------
// CSR build: count -> 3-stage parallel scan -> fill
// ---------------------------------------------------------------------------
__global__ void k_count(const int* __restrict__ dst, int* __restrict__ cnt) {
    int e = blockIdx.x * 256 + threadIdx.x;
    if (e < EE) atomicAdd(&cnt[dst[e]], 1);
}

// stage 1: per-1024-block sums
__global__ __launch_bounds__(1024) void k_scan_part(const int* __restrict__ cnt,
                                                    int* __restrict__ bsum) {
    const int t = threadIdx.x, lane = t & 63, w = t >> 6;
    int i = blockIdx.x * 1024 + t;
    int v = (i < NN) ? cnt[i] : 0;
#pragma unroll
    for (int d = 1; d < 64; d <<= 1) v += __shfl_xor(v, d, 64);
    __shared__ int ws[16];
    if (lane == 0) ws[w] = v;
    __syncthreads();
    if (t == 0) {
        int s = 0;
#pragma unroll
        for (int k = 0; k < 16; ++k) s += ws[k];
        bsum[blockIdx.x] = s;
    }
}

// stage 2: exclusive scan of the 98 block sums (single thread; tiny)
__global__ void k_scan_base(int* __restrict__ bsum, int* __restrict__ offs, int nb) {
    if (threadIdx.x == 0) {
        int run = 0;
        for (int k = 0; k < nb; ++k) {
            int v = bsum[k];
            bsum[k] = run;
            run += v;
        }
        offs[NN] = run;
    }
}

// stage 3: local exclusive scan + base; emits offs, cursor, invd
__global__ __launch_bounds__(1024) void k_scan_final(const int* __restrict__ cnt,
                                                     const int* __restrict__ bsum,
                                                     int* __restrict__ offs,
                                                     int* __restrict__ cursor,
                                                     float* __restrict__ invd) {
    const int t = threadIdx.x, lane = t & 63, w = t >> 6;
    __shared__ int wsum[16], wexcl[16];
    int i = blockIdx.x * 1024 + t;
    int v = (i < NN) ? cnt[i] : 0;
    int s = v;
#pragma unroll
    for (int d = 1; d < 64; d <<= 1) {
        int o = __shfl_up(s, d, 64);
        if (lane >= d) s += o;
    }
    if (lane == 63) wsum[w] = s;
    __syncthreads();
    if (t < 16) {
        int wv = wsum[t];
        int ss = wv;
#pragma unroll
        for (int d = 1; d < 16; d <<= 1) {
            int o = __shfl_up(ss, d, 16);
            if (t >= d) ss += o;
        }
        wexcl[t] = ss - wv;
    }
    __syncthreads();
    if (i < NN) {
        int o = bsum[blockIdx.x] + (s - v) + wexcl[w];
        offs[i] = o;
        cursor[i] = o;
        invd[i] = v > 0 ? 1.f / (float)v : 0.f;  // DGL mean: zero-degree -> 0
    }
}

__global__ void k_fill(const int* __restrict__ src, const int* __restrict__ dst,
                       int* __restrict__ cursor, int* __restrict__ eidsrc) {
    int e = blockIdx.x * 256 + threadIdx.x;
    if (e < EE) {
        int pos = atomicAdd(&cursor[dst[e]], 1);
        eidsrc[pos] = src[e];
    }
}

// ---------------------------------------------------------------------------
// fp32 -> bf16 bulk convert (8 elems/thread)
// ---------------------------------------------------------------------------
__global__ void k_f2bf(const float* __restrict__ in, short* __restrict__ out, int n8) {
    int i = blockIdx.x * 256 + threadIdx.x;
    if (i >= n8) return;
    float4 a = ((const float4*)in)[i * 2];
    float4 b = ((const float4*)in)[i * 2 + 1];
    short8 o;
    o[0] = f2bf(a.x); o[1] = f2bf(a.y); o[2] = f2bf(a.z); o[3] = f2bf(a.w);
    o[4] = f2bf(b.x); o[5] = f2bf(b.y); o[6] = f2bf(b.z); o[7] = f2bf(b.w);
    ((short8*)out)[i] = o;
}

// ---------------------------------------------------------------------------
// bf16 CSR mean-aggregation: F/8 lanes per node, 16 B (8 cols) per lane,
// fp32 accum, 8-deep unrolled.
// ---------------------------------------------------------------------------
template <int F>
__global__ __launch_bounds__(256) void k_gather_bf(
    const short* __restrict__ hbsrc, const int* __restrict__ offs,
    const int* __restrict__ eidsrc, const float* __restrict__ invd,
    short* __restrict__ aggb) {
    constexpr int G = F / 8;  // lanes per node
    int gid = blockIdx.x * 256 + threadIdx.x;
    int node = gid / G;
    int sub = gid % G;
    if (node >= NN) return;
    int beg = offs[node], end = offs[node + 1];
    float iv = invd[node];
    float s[8] = {0.f, 0.f, 0.f, 0.f, 0.f, 0.f, 0.f, 0.f};
    const size_t co = (size_t)sub * 8;
    int p = beg;
    for (; p + 8 <= end; p += 8) {
        int idx[8];
#pragma unroll
        for (int q = 0; q < 8; ++q) idx[q] = eidsrc[p + q];
        short8 r[8];
#pragma unroll
        for (int q = 0; q < 8; ++q)
            r[q] = *(const short8*)(hbsrc + (size_t)idx[q] * F + co);
#pragma unroll
        for (int q = 0; q < 8; ++q)
#pragma unroll
            for (int j = 0; j < 8; ++j) s[j] += bf2f(r[q][j]);
    }
    for (; p + 4 <= end; p += 4) {
        int i0 = eidsrc[p], i1 = eidsrc[p + 1], i2 = eidsrc[p + 2], i3 = eidsrc[p + 3];
        short8 r0 = *(const short8*)(hbsrc + (size_t)i0 * F + co);
        short8 r1 = *(const short8*)(hbsrc + (size_t)i1 * F + co);
        short8 r2 = *(const short8*)(hbsrc + (size_t)i2 * F + co);
        short8 r3 = *(const short8*)(hbsrc + (size_t)i3 * F + co);
#pragma unroll
        for (int j = 0; j < 8; ++j)
            s[j] += (bf2f(r0[j]) + bf2f(r1[j])) + (bf2f(r2[j]) + bf2f(r3[j]));
    }
    for (; p < end; ++p) {
        short8 r = *(const short8*)(hbsrc + (size_t)eidsrc[p] * F + co);
#pragma unroll
        for (int j = 0; j < 8; ++j) s[j] += bf2f(r[j]);
    }
    short8 o;
#pragma unroll
    for (int j = 0; j < 8; ++j) o[j] = f2bf(s[j] * iv);
    *(short8*)(aggb + (size_t)node * F + co) = o;
}

// ---------------------------------------------------------------------------
// Unified weight pre-pack into bf16 MFMA-B fragment order.
// ---------------------------------------------------------------------------
__device__ __forceinline__ void packW(const float* W, short* Wp, int local, int kbase) {
    int k = local >> 7, col = local & 127;
    int gk = k + kbase;
    int kc = gk >> 5, kw = gk & 31, bp = kw >> 3, j = kw & 7;
    int cb = col >> 4, n = col & 15;
    Wp[kc * 4096 + (cb * 64 + bp * 16 + n) * 8 + j] = f2bf(W[k * 128 + col]);
}

__global__ void k_pack_all(const float* __restrict__ We1, const float* __restrict__ Ws1,
                           const float* __restrict__ Wn1, const float* __restrict__ Ws2,
                           const float* __restrict__ Wn2, const float* __restrict__ We2,
                           short* __restrict__ Wp_e, short* __restrict__ Wp1,
                           short* __restrict__ Wp2, short* __restrict__ Wp2e) {
    int idx = blockIdx.x * 256 + threadIdx.x;
    if (idx < 40960) {
        packW(We1, Wp_e, idx, 0);
    } else if (idx < 49152) {
        packW(Ws1, Wp1, idx - 40960, 0);
    } else if (idx < 57344) {
        packW(Wn1, Wp1, idx - 49152, 64);
    } else if (idx < 73728) {
        packW(Ws2, Wp2, idx - 57344, 0);
    } else if (idx < 90112) {
        packW(Wn2, Wp2, idx - 73728, 128);
    } else if (idx < 92160) {
        int local = idx - 90112;  // over 128 k x 16 n
        int k = local >> 4, n = local & 15;
        float val = (n < 8) ? We2[k * 8 + n] : 0.f;
        int kc2 = k >> 5, kl = k & 31, bp = kl >> 3, j = kl & 7;
        Wp2e[(kc2 * 64 + bp * 16 + n) * 8 + j] = f2bf(val);
    }
}

// ---------------------------------------------------------------------------
// bf16 MFMA node GEMM: counted-vmcnt 3-buffer pipeline + fused col-stats.
// outz[N,128] (bf16) = [A1b | A2b] @ Wp + bias; stats from exact fp32 acc.
// ---------------------------------------------------------------------------
template <int KC1, int KC2>
__global__ __launch_bounds__(256) void k_node_mfma(
    const short* __restrict__ A1, const short* __restrict__ A2,
    const short* __restrict__ Wp, const float* __restrict__ bias,
    short* __restrict__ outz, float* __restrict__ stats) {
    __shared__ __align__(16) short sbuf[24576];  // 3 × (A 4096 | B 4096)
    __shared__ float bs[128];
    __shared__ float reds[4][128], redss[4][128];
    const int t = threadIdx.x;
    if (t < 128) bs[t] = bias[t];
    const int rowbase = blockIdx.x * 128;
    const int lane = t & 63, w = t >> 6;
    const int fo = (lane >> 4) * 16 + (lane & 15);
    __syncthreads();  // bs ready

    auto NSTAGE = [&](int kc, short* Ad, short* Bd) {
        const short* src;
        int kst, kloc;
        if (kc < KC1) { src = A1; kst = KC1 * 32; kloc = kc * 32; }
        else          { src = A2; kst = KC2 * 32; kloc = (kc - KC1) * 32; }
#pragma unroll
        for (int p = 0; p < 2; ++p) {
            int s = t + p * 256;
            int b = (s >> 4) & 3;
            int row = rowbase + ((s >> 6) << 4) + (s & 15);
            gload_lds16(src + (size_t)row * kst + kloc + b * 8, Ad + s * 8);
            gload_lds16(Wp + (size_t)kc * 4096 + s * 8, Bd + s * 8);
        }
    };

    f32x4 acc[2][8];
#pragma unroll
    for (int i = 0; i < 2; ++i)
#pragma unroll
        for (int j = 0; j < 8; ++j) acc[i][j] = (f32x4){0.f, 0.f, 0.f, 0.f};

    constexpr int KC = KC1 + KC2;
    NSTAGE(0, sbuf, sbuf + 4096);
    NSTAGE(1, sbuf + 8192, sbuf + 8192 + 4096);
    for (int kc = 0; kc < KC; ++kc) {
        if (kc < KC - 1)
            asm volatile("s_waitcnt vmcnt(4) lgkmcnt(0)" ::: "memory");
        else
            asm volatile("s_waitcnt vmcnt(0) lgkmcnt(0)" ::: "memory");
        __builtin_amdgcn_s_barrier();
        __builtin_amdgcn_sched_barrier(0);
        if (kc + 2 < KC) {
            short* An = sbuf + ((kc + 2) % 3) * 8192;
            NSTAGE(kc + 2, An, An + 4096);
        }
        short* Ac = sbuf + (kc % 3) * 8192;
        short* Bc = Ac + 4096;
        short8 a0 = *(const short8*)(Ac + (2 * w * 64 + fo) * 8);
        short8 a1 = *(const short8*)(Ac + ((2 * w + 1) * 64 + fo) * 8);
#pragma unroll
        for (int cb = 0; cb < 8; ++cb) {
            short8 bfr = *(const short8*)(Bc + (cb * 64 + fo) * 8);
            acc[0][cb] = __builtin_amdgcn_mfma_f32_16x16x32_bf16(a0, bfr, acc[0][cb], 0, 0, 0);
            acc[1][cb] = __builtin_amdgcn_mfma_f32_16x16x32_bf16(a1, bfr, acc[1][cb], 0, 0, 0);
        }
    }
    __syncthreads();

    // epilogue: bias-add, bf16 store, per-column partial stats (fp32-exact)
    float cs[8], css[8];
#pragma unroll
    for (int cb = 0; cb < 8; ++cb) { cs[cb] = 0.f; css[cb] = 0.f; }
#pragma unroll
    for (int rb2 = 0; rb2 < 2; ++rb2) {
        int rloc = 32 * w + rb2 * 16 + ((lane >> 4) << 2);
#pragma unroll
        for (int cb = 0; cb < 8; ++cb) {
            int col = cb * 16 + (lane & 15);
            float bb = bs[col];
#pragma unroll
            for (int i = 0; i < 4; ++i) {
                int row = rowbase + rloc + i;
                if (row < NN) {
                    float v = acc[rb2][cb][i] + bb;
                    outz[(size_t)row * 128 + col] = f2bf(v);
                    cs[cb] += v;
                    css[cb] += v * v;
                }
            }
        }
    }
#pragma unroll
    for (int cb = 0; cb < 8; ++cb) {
        cs[cb] += __shfl_xor(cs[cb], 16);
        cs[cb] += __shfl_xor(cs[cb], 32);
        css[cb] += __shfl_xor(css[cb], 16);
        css[cb] += __shfl_xor(css[cb], 32);
    }
    if (lane < 16) {
#pragma unroll
        for (int cb = 0; cb < 8; ++cb) {
            reds[w][cb * 16 + lane] = cs[cb];
            redss[w][cb * 16 + lane] = css[cb];
        }
    }
    __syncthreads();
    if (t < 128) {
        atomicAdd(&stats[t], reds[0][t] + reds[1][t] + reds[2][t] + reds[3][t]);
    } else {
        int c = t - 128;
        atomicAdd(&stats[128 + c], redss[0][c] + redss[1][c] + redss[2][c] + redss[3][c]);
    }
}

// BN + ReLU over bf16 z -> bf16 out; scale/shift computed once per block.
__global__ void k_bnrelu_bf16(const short* __restrict__ z, const float* __restrict__ stats,
                              const float* __restrict__ g, const float* __restrict__ bt,
                              short* __restrict__ hb) {
    __shared__ float a_sh[128], b_sh[128];
    const int t = threadIdx.x;
    if (t < 128) {
        float mu = stats[t] * (1.f / NN);
        float var = stats[128 + t] * (1.f / NN) - mu * mu;  // biased (matches ref)
        float a = g[t] * rsqrtf(var + BN_EPS);
        a_sh[t] = a;
        b_sh[t] = bt[t] - mu * a;
    }
    __syncthreads();
    int gid = blockIdx.x * 256 + t;  // over NN*16 groups of 8
    if (gid >= NN * 16) return;
    int c0 = (gid & 15) * 8;
    short8 zv = reinterpret_cast<const short8*>(z)[gid];
    short8 o;
#pragma unroll
    for (int j = 0; j < 8; ++j)
        o[j] = f2bf(fmaxf(fmaf(a_sh[c0 + j], bf2f(zv[j]), b_sh[c0 + j]), 0.f));
    reinterpret_cast<short8*>(hb)[gid] = o;
}

// ---------------------------------------------------------------------------
// MFMA edge MLP: 256 edges/block, 8 waves, counted-vmcnt 3-buffer pipeline,
// setprio around MFMA cluster. B (We1) traffic per edge halves vs 128-tile.
// Per-stage loads/lane: A 2 + B 1 = 3 -> steady vmcnt(3); kc=8 ef path
// self-drains older loads -> vmcnt(1); kc=9 -> vmcnt(0).
// ---------------------------------------------------------------------------
__global__ __launch_bounds__(512) void k_edge_mfma(
    const short* __restrict__ hb, const float* __restrict__ ef,
    const short* __restrict__ Wp, const short* __restrict__ Wp2e,
    const float* __restrict__ be1, const float* __restrict__ be2,
    const int* __restrict__ uu, const int* __restrict__ vv,
    float* __restrict__ out) {
    // staging: 3 × (A 16KB | B 8KB) = 73728 B  ∪  Hid[256][136] = 69632 B
    __shared__ __align__(16) short smem[36864];
    __shared__ float be1s[128];
    __shared__ int suv[512];
    const int t = threadIdx.x;
    const int eb = blockIdx.x * 256;
    if (t < 256) {
        suv[t] = uu[eb + t];
        suv[256 + t] = vv[eb + t];
    }
    if (t < 128) be1s[t] = be1[t];
    __syncthreads();

    const int lane = t & 63, w = t >> 6;  // w in [0,8)
    const int fo = (lane >> 4) * 16 + (lane & 15);
    const int srow = t >> 1;      // ef-staging row (0..255)
    const int sb0 = (t & 1) * 2;  // ef-staging k-subblock base
    const int sslotbase = (srow >> 4) * 64 + (srow & 15);

    // preload layer-2 B-frags (4 KB, L2-resident)
    short8 b2f[4];
#pragma unroll
    for (int kc2 = 0; kc2 < 4; ++kc2)
        b2f[kc2] = *(const short8*)(Wp2e + (kc2 * 64 + fo) * 8);

    auto STAGE = [&](int kc, short* Ad, short* Bd) {
        if (kc < 8) {
#pragma unroll
            for (int p = 0; p < 2; ++p) {
                int s = t + p * 512;  // [0,1024): 256 rows x 4 k-subblocks
                int b = (s >> 4) & 3;
                int row = ((s >> 6) << 4) + (s & 15);
                const short* gsrc =
                    hb + (size_t)suv[(kc >= 4) * 256 + row] * 128 + (kc & 3) * 32 + b * 8;
                gload_lds16(gsrc, Ad + s * 8);
            }
        } else {
            const float* er = ef + (size_t)(eb + srow) * 64 + (kc - 8) * 32;
#pragma unroll
            for (int p = 0; p < 2; ++p) {
                int b = sb0 + p;
                float4 f0 = *(const float4*)(er + b * 8);
                float4 f1 = *(const float4*)(er + b * 8 + 4);
                short8 v8;
                v8[0] = f2bf(f0.x); v8[1] = f2bf(f0.y);
                v8[2] = f2bf(f0.z); v8[3] = f2bf(f0.w);
                v8[4] = f2bf(f1.x); v8[5] = f2bf(f1.y);
                v8[6] = f2bf(f1.z); v8[7] = f2bf(f1.w);
                *(short8*)(Ad + (sslotbase + b * 16) * 8) = v8;
            }
        }
        // B: 8 KB = 512 x 16 B -> exactly one DMA per thread
        gload_lds16(Wp + (size_t)kc * 4096 + t * 8, Bd + t * 8);
    };

    f32x4 acc[2][8];
#pragma unroll
    for (int i = 0; i < 2; ++i)
#pragma unroll
        for (int j = 0; j < 8; ++j) acc[i][j] = (f32x4){0.f, 0.f, 0.f, 0.f};

    // prologue: 2 stages in flight (buffers 0,1; stride 12288 shorts = 24 KB)
    STAGE(0, smem, smem + 8192);
    STAGE(1, smem + 12288, smem + 12288 + 8192);
    for (int kc = 0; kc < 10; ++kc) {
        if (kc < 8)
            asm volatile("s_waitcnt vmcnt(3) lgkmcnt(0)" ::: "memory");
        else if (kc == 8)
            asm volatile("s_waitcnt vmcnt(1) lgkmcnt(0)" ::: "memory");
        else
            asm volatile("s_waitcnt vmcnt(0) lgkmcnt(0)" ::: "memory");
        __builtin_amdgcn_s_barrier();
        __builtin_amdgcn_sched_barrier(0);
        if (kc + 2 < 10) {
            short* An = smem + ((kc + 2) % 3) * 12288;
            STAGE(kc + 2, An, An + 8192);
        }
        short* Ac = smem + (kc % 3) * 12288;
        short* Bc = Ac + 8192;
        short8 afr0 = *(const short8*)(Ac + ((2 * w) * 64 + fo) * 8);
        short8 afr1 = *(const short8*)(Ac + ((2 * w + 1) * 64 + fo) * 8);
        __builtin_amdgcn_s_setprio(1);
#pragma unroll
        for (int cb = 0; cb < 8; ++cb) {
            short8 bfr = *(const short8*)(Bc + (cb * 64 + fo) * 8);
            acc[0][cb] = __builtin_amdgcn_mfma_f32_16x16x32_bf16(afr0, bfr, acc[0][cb], 0, 0, 0);
            acc[1][cb] = __builtin_amdgcn_mfma_f32_16x16x32_bf16(afr1, bfr, acc[1][cb], 0, 0, 0);
        }
        __builtin_amdgcn_s_setprio(0);
    }
    __syncthreads();  // all waves done with staging region before Hid overwrite

    // ---- epilogue 1: bias + relu -> Hid[256][136] bf16 (reuses stage region) ----
    short* Hid = smem;
#pragma unroll
    for (int rb2 = 0; rb2 < 2; ++rb2)
#pragma unroll
        for (int cb = 0; cb < 8; ++cb) {
            int col = cb * 16 + (lane & 15);
            int rbase = 32 * w + rb2 * 16 + ((lane >> 4) << 2);
            float bb = be1s[col];
#pragma unroll
            for (int i = 0; i < 4; ++i)
                Hid[(rbase + i) * 136 + col] = f2bf(fmaxf(acc[rb2][cb][i] + bb, 0.f));
        }
    __syncthreads();

    // ---- layer 2 via MFMA: out[e][0..7] = Hid @ We2p + be2 ----
#pragma unroll
    for (int rf = 0; rf < 2; ++rf) {
        f32x4 a2 = (f32x4){0.f, 0.f, 0.f, 0.f};
        const int rbl = 32 * w + 16 * rf + (lane & 15);
#pragma unroll
        for (int kc2 = 0; kc2 < 4; ++kc2) {
            short8 af = *(const short8*)(Hid + rbl * 136 + kc2 * 32 + 8 * (lane >> 4));
            a2 = __builtin_amdgcn_mfma_f32_16x16x32_bf16(af, b2f[kc2], a2, 0, 0, 0);
        }
        int col = lane & 15;
        if (col < 8) {
            int r0 = eb + 32 * w + 16 * rf + 4 * (lane >> 4);
            float bb = be2[col];
#pragma unroll
            for (int i = 0; i < 4; ++i)
                out[(size_t)(r0 + i) * 8 + col] = a2[i] + bb;
        }
    }
}

// ---------------------------------------------------------------------------
extern "C" void kernel_launch(void* const* d_in, const int* in_sizes, int n_in,
                              void* d_out, int out_size, void* d_ws, size_t ws_size,
                              hipStream_t stream) {
    const float* x   = (const float*)d_in[0];
    const float* ef  = (const float*)d_in[1];
    const float* Ws1 = (const float*)d_in[2];
    const float* Wn1 = (const float*)d_in[3];
    const float* b1  = (const float*)d_in[4];
    const float* g1  = (const float*)d_in[5];
    const float* bt1 = (const float*)d_in[6];
    const float* Ws2 = (const float*)d_in[7];
    const float* Wn2 = (const float*)d_in[8];
    const float* b2  = (const float*)d_in[9];
    const float* g2  = (const float*)d_in[10];
    const float* bt2 = (const float*)d_in[11];
    const float* We1 = (const float*)d_in[12];
    const float* be1 = (const float*)d_in[13];
    const float* We2 = (const float*)d_in[14];
    const float* be2 = (const float*)d_in[15];
    const int* src = (const int*)d_in[16];
    const int* dst = (const int*)d_in[17];
    const int* u   = (const int*)d_in[18];
    const int* v   = (const int*)d_in[19];
    float* out = (float*)d_out;

    // Workspace (~85 MB). z (pre-BN, bf16) lives in d_out's first half
    // (dead before the edge head overwrites d_out). hb aliases xb+agg1b.
    char* p = (char*)d_ws;
    auto take = [&](size_t bytes) {
        char* r = p;
        p += (bytes + 255) & ~(size_t)255;
        return r;
    };
    int* cnt     = (int*)take(NN * 4);       // adjacent to stats: one memset
    float* stats = (float*)take(512 * 4);    // [0:256)=layer1, [256:512)=layer2
    float* invd  = (float*)take(NN * 4);
    int* offs    = (int*)take((NN + 1) * 4);
    int* cursor  = (int*)take(NN * 4);
    int* bsum    = (int*)take(128 * 4);
    int* eidsrc  = (int*)take((size_t)EE * 4);
    short* Wp_e  = (short*)take(320 * 128 * 2);
    short* Wp1   = (short*)take(128 * 128 * 2);
    short* Wp2   = (short*)take(256 * 128 * 2);
    short* Wp2e  = (short*)take(256 * 8 * 2);
    short* xb    = (short*)take((size_t)NN * 64 * 2);
    short* agg1b = (short*)take((size_t)NN * 64 * 2);
    short* h1b   = (short*)take((size_t)NN * 128 * 2);
    short* agg2b = (short*)take((size_t)NN * 128 * 2);
    take(65536);  // pad: node GEMMs read up to ~25 KB past last row
    short* zb = (short*)out;  // bf16 pre-BN z, both layers (25.6 MB of d_out)
    short* hb = xb;           // 25.6 MB union of xb+agg1b

    const int NB = (NN + 1023) / 1024;  // 98 scan blocks

    // ---- CSR build + weight pre-pack + x -> bf16 ----
    hipMemsetAsync(cnt, 0, ((char*)stats - (char*)cnt) + 512 * 4, stream);
    k_count<<<(EE + 255) / 256, 256, 0, stream>>>(dst, cnt);
    k_scan_part<<<NB, 1024, 0, stream>>>(cnt, bsum);
    k_scan_base<<<1, 64, 0, stream>>>(bsum, offs, NB);
    k_scan_final<<<NB, 1024, 0, stream>>>(cnt, bsum, offs, cursor, invd);
    k_fill<<<(EE + 255) / 256, 256, 0, stream>>>(src, dst, cursor, eidsrc);
    k_pack_all<<<360, 256, 0, stream>>>(We1, Ws1, Wn1, Ws2, Wn2, We2, Wp_e, Wp1, Wp2, Wp2e);
    k_f2bf<<<(NN * 8 + 255) / 256, 256, 0, stream>>>(x, xb, NN * 8);

    // ---- layer 1 (bf16 inputs, fp32 accum/stats; stats fused in GEMM) ----
    k_gather_bf<64><<<(NN * 8 + 255) / 256, 256, 0, stream>>>(xb, offs, eidsrc, invd, agg1b);
    k_node_mfma<2, 2><<<(NN + 127) / 128, 256, 0, stream>>>(xb, agg1b, Wp1, b1, zb, stats);
    k_bnrelu_bf16<<<(NN * 16 + 255) / 256, 256, 0, stream>>>(zb, stats, g1, bt1, h1b);

    // ---- layer 2 ----
    k_gather_bf<128><<<(NN * 16 + 255) / 256, 256, 0, stream>>>(h1b, offs, eidsrc, invd, agg2b);
    k_node_mfma<4, 4><<<(NN + 127) / 128, 256, 0, stream>>>(h1b, agg2b, Wp2, b2, zb, stats + 256);
    k_bnrelu_bf16<<<(NN * 16 + 255) / 256, 256, 0, stream>>>(zb, stats + 256, g2, bt2, hb);

    // ---- edge head (bf16 MFMA, 256-edge tile, counted-vmcnt pipeline) ----
    k_edge_mfma<<<EE / 256, 512, 0, stream>>>(hb, ef, Wp_e, Wp2e, be1, be2, u, v, out);
}

// Round 12
// 637.764 us; speedup vs baseline: 1.1191x; 1.1191x over previous
//
#include <hip/hip_runtime.h>

// Problem constants (fixed by the reference).
#define NN 100000
#define EE 1600000
// D_IN=64, H=128, E_IN=64, C=8
constexpr float BN_EPS = 1e-5f;

typedef __attribute__((ext_vector_type(8))) short short8;
typedef __attribute__((ext_vector_type(4))) float f32x4;

__device__ __forceinline__ short f2bf(float f) {  // RNE f32 -> bf16
    unsigned u = __float_as_uint(f);
    u += 0x7fff + ((u >> 16) & 1);
    return (short)(u >> 16);
}
__device__ __forceinline__ float bf2f(short s) {
    return __uint_as_float(((unsigned)(unsigned short)s) << 16);
}

// async global->LDS DMA, 16 B per lane. LDS dest must be base + lane*16
// within each wave (guaranteed by construction at all call sites).
typedef __attribute__((address_space(1))) const unsigned int guint;
typedef __attribute__((address_space(3))) unsigned int luint;
__device__ __forceinline__ void gload_lds16(const void* g, void* l) {
    __builtin_amdgcn_global_load_lds((guint*)g, (luint*)l, 16, 0, 0);
}

// ---------------------------------------------------------------------------
// CSR build: count -> 3-stage parallel scan -> fill
// ---------------------------------------------------------------------------
__global__ void k_count(const int* __restrict__ dst, int* __restrict__ cnt) {
    int e = blockIdx.x * 256 + threadIdx.x;
    if (e < EE) atomicAdd(&cnt[dst[e]], 1);
}

// stage 1: per-1024-block sums
__global__ __launch_bounds__(1024) void k_scan_part(const int* __restrict__ cnt,
                                                    int* __restrict__ bsum) {
    const int t = threadIdx.x, lane = t & 63, w = t >> 6;
    int i = blockIdx.x * 1024 + t;
    int v = (i < NN) ? cnt[i] : 0;
#pragma unroll
    for (int d = 1; d < 64; d <<= 1) v += __shfl_xor(v, d, 64);
    __shared__ int ws[16];
    if (lane == 0) ws[w] = v;
    __syncthreads();
    if (t == 0) {
        int s = 0;
#pragma unroll
        for (int k = 0; k < 16; ++k) s += ws[k];
        bsum[blockIdx.x] = s;
    }
}

// stage 2: exclusive scan of the 98 block sums (single thread; tiny)
__global__ void k_scan_base(int* __restrict__ bsum, int* __restrict__ offs, int nb) {
    if (threadIdx.x == 0) {
        int run = 0;
        for (int k = 0; k < nb; ++k) {
            int v = bsum[k];
            bsum[k] = run;
            run += v;
        }
        offs[NN] = run;
    }
}

// stage 3: local exclusive scan + base; emits offs, cursor, invd
__global__ __launch_bounds__(1024) void k_scan_final(const int* __restrict__ cnt,
                                                     const int* __restrict__ bsum,
                                                     int* __restrict__ offs,
                                                     int* __restrict__ cursor,
                                                     float* __restrict__ invd) {
    const int t = threadIdx.x, lane = t & 63, w = t >> 6;
    __shared__ int wsum[16], wexcl[16];
    int i = blockIdx.x * 1024 + t;
    int v = (i < NN) ? cnt[i] : 0;
    int s = v;
#pragma unroll
    for (int d = 1; d < 64; d <<= 1) {
        int o = __shfl_up(s, d, 64);
        if (lane >= d) s += o;
    }
    if (lane == 63) wsum[w] = s;
    __syncthreads();
    if (t < 16) {
        int wv = wsum[t];
        int ss = wv;
#pragma unroll
        for (int d = 1; d < 16; d <<= 1) {
            int o = __shfl_up(ss, d, 16);
            if (t >= d) ss += o;
        }
        wexcl[t] = ss - wv;
    }
    __syncthreads();
    if (i < NN) {
        int o = bsum[blockIdx.x] + (s - v) + wexcl[w];
        offs[i] = o;
        cursor[i] = o;
        invd[i] = v > 0 ? 1.f / (float)v : 0.f;  // DGL mean: zero-degree -> 0
    }
}

__global__ void k_fill(const int* __restrict__ src, const int* __restrict__ dst,
                       int* __restrict__ cursor, int* __restrict__ eidsrc) {
    int e = blockIdx.x * 256 + threadIdx.x;
    if (e < EE) {
        int pos = atomicAdd(&cursor[dst[e]], 1);
        eidsrc[pos] = src[e];
    }
}

// ---------------------------------------------------------------------------
// bf16 CSR mean-aggregation: F/8 lanes per node, 16 B (8 cols) per lane,
// fp32 accum, 8-deep unrolled.
// ---------------------------------------------------------------------------
template <int F>
__global__ __launch_bounds__(256) void k_gather_bf(
    const short* __restrict__ hbsrc, const int* __restrict__ offs,
    const int* __restrict__ eidsrc, const float* __restrict__ invd,
    short* __restrict__ aggb) {
    constexpr int G = F / 8;  // lanes per node
    int gid = blockIdx.x * 256 + threadIdx.x;
    int node = gid / G;
    int sub = gid % G;
    if (node >= NN) return;
    int beg = offs[node], end = offs[node + 1];
    float iv = invd[node];
    float s[8] = {0.f, 0.f, 0.f, 0.f, 0.f, 0.f, 0.f, 0.f};
    const size_t co = (size_t)sub * 8;
    int p = beg;
    for (; p + 8 <= end; p += 8) {
        int idx[8];
#pragma unroll
        for (int q = 0; q < 8; ++q) idx[q] = eidsrc[p + q];
        short8 r[8];
#pragma unroll
        for (int q = 0; q < 8; ++q)
            r[q] = *(const short8*)(hbsrc + (size_t)idx[q] * F + co);
#pragma unroll
        for (int q = 0; q < 8; ++q)
#pragma unroll
            for (int j = 0; j < 8; ++j) s[j] += bf2f(r[q][j]);
    }
    for (; p + 4 <= end; p += 4) {
        int i0 = eidsrc[p], i1 = eidsrc[p + 1], i2 = eidsrc[p + 2], i3 = eidsrc[p + 3];
        short8 r0 = *(const short8*)(hbsrc + (size_t)i0 * F + co);
        short8 r1 = *(const short8*)(hbsrc + (size_t)i1 * F + co);
        short8 r2 = *(const short8*)(hbsrc + (size_t)i2 * F + co);
        short8 r3 = *(const short8*)(hbsrc + (size_t)i3 * F + co);
#pragma unroll
        for (int j = 0; j < 8; ++j)
            s[j] += (bf2f(r0[j]) + bf2f(r1[j])) + (bf2f(r2[j]) + bf2f(r3[j]));
    }
    for (; p < end; ++p) {
        short8 r = *(const short8*)(hbsrc + (size_t)eidsrc[p] * F + co);
#pragma unroll
        for (int j = 0; j < 8; ++j) s[j] += bf2f(r[j]);
    }
    short8 o;
#pragma unroll
    for (int j = 0; j < 8; ++j) o[j] = f2bf(s[j] * iv);
    *(short8*)(aggb + (size_t)node * F + co) = o;
}

// ---------------------------------------------------------------------------
// Unified weight pre-pack into bf16 MFMA-B fragment order, PLUS x->bf16
// bulk convert appended to the same grid (independent index ranges).
// ---------------------------------------------------------------------------
__device__ __forceinline__ void packW(const float* W, short* Wp, int local, int kbase) {
    int k = local >> 7, col = local & 127;
    int gk = k + kbase;
    int kc = gk >> 5, kw = gk & 31, bp = kw >> 3, j = kw & 7;
    int cb = col >> 4, n = col & 15;
    Wp[kc * 4096 + (cb * 64 + bp * 16 + n) * 8 + j] = f2bf(W[k * 128 + col]);
}

__global__ void k_pack_all(const float* __restrict__ We1, const float* __restrict__ Ws1,
                           const float* __restrict__ Wn1, const float* __restrict__ Ws2,
                           const float* __restrict__ Wn2, const float* __restrict__ We2,
                           short* __restrict__ Wp_e, short* __restrict__ Wp1,
                           short* __restrict__ Wp2, short* __restrict__ Wp2e,
                           const float* __restrict__ x, short* __restrict__ xb) {
    int idx = blockIdx.x * 256 + threadIdx.x;
    if (idx < 40960) {
        packW(We1, Wp_e, idx, 0);
    } else if (idx < 49152) {
        packW(Ws1, Wp1, idx - 40960, 0);
    } else if (idx < 57344) {
        packW(Wn1, Wp1, idx - 49152, 64);
    } else if (idx < 73728) {
        packW(Ws2, Wp2, idx - 57344, 0);
    } else if (idx < 90112) {
        packW(Wn2, Wp2, idx - 73728, 128);
    } else if (idx < 92160) {
        int local = idx - 90112;  // over 128 k x 16 n
        int k = local >> 4, n = local & 15;
        float val = (n < 8) ? We2[k * 8 + n] : 0.f;
        int kc2 = k >> 5, kl = k & 31, bp = kl >> 3, j = kl & 7;
        Wp2e[(kc2 * 64 + bp * 16 + n) * 8 + j] = f2bf(val);
    } else if (idx < 92160 + NN * 8) {
        int i = idx - 92160;  // groups of 8 floats
        float4 a = ((const float4*)x)[i * 2];
        float4 b = ((const float4*)x)[i * 2 + 1];
        short8 o;
        o[0] = f2bf(a.x); o[1] = f2bf(a.y); o[2] = f2bf(a.z); o[3] = f2bf(a.w);
        o[4] = f2bf(b.x); o[5] = f2bf(b.y); o[6] = f2bf(b.z); o[7] = f2bf(b.w);
        ((short8*)xb)[i] = o;
    }
}

// ---------------------------------------------------------------------------
// bf16 MFMA node GEMM: counted-vmcnt 3-buffer pipeline + fused col-stats.
// outz[N,128] (bf16) = [A1b | A2b] @ Wp + bias; stats from exact fp32 acc.
// ---------------------------------------------------------------------------
template <int KC1, int KC2>
__global__ __launch_bounds__(256) void k_node_mfma(
    const short* __restrict__ A1, const short* __restrict__ A2,
    const short* __restrict__ Wp, const float* __restrict__ bias,
    short* __restrict__ outz, float* __restrict__ stats) {
    __shared__ __align__(16) short sbuf[24576];  // 3 × (A 4096 | B 4096)
    __shared__ float bs[128];
    __shared__ float reds[4][128], redss[4][128];
    const int t = threadIdx.x;
    if (t < 128) bs[t] = bias[t];
    const int rowbase = blockIdx.x * 128;
    const int lane = t & 63, w = t >> 6;
    const int fo = (lane >> 4) * 16 + (lane & 15);
    __syncthreads();  // bs ready

    auto NSTAGE = [&](int kc, short* Ad, short* Bd) {
        const short* src;
        int kst, kloc;
        if (kc < KC1) { src = A1; kst = KC1 * 32; kloc = kc * 32; }
        else          { src = A2; kst = KC2 * 32; kloc = (kc - KC1) * 32; }
#pragma unroll
        for (int p = 0; p < 2; ++p) {
            int s = t + p * 256;
            int b = (s >> 4) & 3;
            int row = rowbase + ((s >> 6) << 4) + (s & 15);
            gload_lds16(src + (size_t)row * kst + kloc + b * 8, Ad + s * 8);
            gload_lds16(Wp + (size_t)kc * 4096 + s * 8, Bd + s * 8);
        }
    };

    f32x4 acc[2][8];
#pragma unroll
    for (int i = 0; i < 2; ++i)
#pragma unroll
        for (int j = 0; j < 8; ++j) acc[i][j] = (f32x4){0.f, 0.f, 0.f, 0.f};

    constexpr int KC = KC1 + KC2;
    NSTAGE(0, sbuf, sbuf + 4096);
    NSTAGE(1, sbuf + 8192, sbuf + 8192 + 4096);
    for (int kc = 0; kc < KC; ++kc) {
        if (kc < KC - 1)
            asm volatile("s_waitcnt vmcnt(4) lgkmcnt(0)" ::: "memory");
        else
            asm volatile("s_waitcnt vmcnt(0) lgkmcnt(0)" ::: "memory");
        __builtin_amdgcn_s_barrier();
        __builtin_amdgcn_sched_barrier(0);
        if (kc + 2 < KC) {
            short* An = sbuf + ((kc + 2) % 3) * 8192;
            NSTAGE(kc + 2, An, An + 4096);
        }
        short* Ac = sbuf + (kc % 3) * 8192;
        short* Bc = Ac + 4096;
        short8 a0 = *(const short8*)(Ac + (2 * w * 64 + fo) * 8);
        short8 a1 = *(const short8*)(Ac + ((2 * w + 1) * 64 + fo) * 8);
#pragma unroll
        for (int cb = 0; cb < 8; ++cb) {
            short8 bfr = *(const short8*)(Bc + (cb * 64 + fo) * 8);
            acc[0][cb] = __builtin_amdgcn_mfma_f32_16x16x32_bf16(a0, bfr, acc[0][cb], 0, 0, 0);
            acc[1][cb] = __builtin_amdgcn_mfma_f32_16x16x32_bf16(a1, bfr, acc[1][cb], 0, 0, 0);
        }
    }
    __syncthreads();

    // epilogue: bias-add, bf16 store, per-column partial stats (fp32-exact)
    float cs[8], css[8];
#pragma unroll
    for (int cb = 0; cb < 8; ++cb) { cs[cb] = 0.f; css[cb] = 0.f; }
#pragma unroll
    for (int rb2 = 0; rb2 < 2; ++rb2) {
        int rloc = 32 * w + rb2 * 16 + ((lane >> 4) << 2);
#pragma unroll
        for (int cb = 0; cb < 8; ++cb) {
            int col = cb * 16 + (lane & 15);
            float bb = bs[col];
#pragma unroll
            for (int i = 0; i < 4; ++i) {
                int row = rowbase + rloc + i;
                if (row < NN) {
                    float v = acc[rb2][cb][i] + bb;
                    outz[(size_t)row * 128 + col] = f2bf(v);
                    cs[cb] += v;
                    css[cb] += v * v;
                }
            }
        }
    }
#pragma unroll
    for (int cb = 0; cb < 8; ++cb) {
        cs[cb] += __shfl_xor(cs[cb], 16);
        cs[cb] += __shfl_xor(cs[cb], 32);
        css[cb] += __shfl_xor(css[cb], 16);
        css[cb] += __shfl_xor(css[cb], 32);
    }
    if (lane < 16) {
#pragma unroll
        for (int cb = 0; cb < 8; ++cb) {
            reds[w][cb * 16 + lane] = cs[cb];
            redss[w][cb * 16 + lane] = css[cb];
        }
    }
    __syncthreads();
    if (t < 128) {
        atomicAdd(&stats[t], reds[0][t] + reds[1][t] + reds[2][t] + reds[3][t]);
    } else {
        int c = t - 128;
        atomicAdd(&stats[128 + c], redss[0][c] + redss[1][c] + redss[2][c] + redss[3][c]);
    }
}

// BN + ReLU over bf16 z -> bf16 out; scale/shift computed once per block.
__global__ void k_bnrelu_bf16(const short* __restrict__ z, const float* __restrict__ stats,
                              const float* __restrict__ g, const float* __restrict__ bt,
                              short* __restrict__ hb) {
    __shared__ float a_sh[128], b_sh[128];
    const int t = threadIdx.x;
    if (t < 128) {
        float mu = stats[t] * (1.f / NN);
        float var = stats[128 + t] * (1.f / NN) - mu * mu;  // biased (matches ref)
        float a = g[t] * rsqrtf(var + BN_EPS);
        a_sh[t] = a;
        b_sh[t] = bt[t] - mu * a;
    }
    __syncthreads();
    int gid = blockIdx.x * 256 + t;  // over NN*16 groups of 8
    if (gid >= NN * 16) return;
    int c0 = (gid & 15) * 8;
    short8 zv = reinterpret_cast<const short8*>(z)[gid];
    short8 o;
#pragma unroll
    for (int j = 0; j < 8; ++j)
        o[j] = f2bf(fmaxf(fmaf(a_sh[c0 + j], bf2f(zv[j]), b_sh[c0 + j]), 0.f));
    reinterpret_cast<short8*>(hb)[gid] = o;
}

// ---------------------------------------------------------------------------
// MFMA edge MLP (R10-proven): 128 edges/block, 4 waves, counted-vmcnt
// 3-buffer pipeline, prefetch distance 2. Reverted from the 256-edge R11
// variant (74.5 KB LDS -> 2 blocks/CU + 8-wave lockstep = regression).
// ---------------------------------------------------------------------------
__global__ __launch_bounds__(256) void k_edge_mfma(
    const short* __restrict__ hb, const float* __restrict__ ef,
    const short* __restrict__ Wp, const short* __restrict__ Wp2e,
    const float* __restrict__ be1, const float* __restrict__ be2,
    const int* __restrict__ uu, const int* __restrict__ vv,
    float* __restrict__ out) {
    // 49152 B: staging buf[3] × (A 8KB|B 8KB)  ∪  Hid[128][136] (34816 B)
    __shared__ __align__(16) short smem[24576];
    __shared__ float be1s[128];
    __shared__ int suv[256];
    const int t = threadIdx.x;
    const int eb = blockIdx.x * 128;
    if (t < 128) {
        suv[t] = uu[eb + t];
        suv[128 + t] = vv[eb + t];
        be1s[t] = be1[t];
    }
    __syncthreads();

    const int lane = t & 63, w = t >> 6;
    const int fo = (lane >> 4) * 16 + (lane & 15);
    const int srow = t >> 1;      // ef-staging row
    const int sb0 = (t & 1) * 2;  // ef-staging k-subblock base
    const int sslotbase = (srow >> 4) * 64 + (srow & 15);

    // preload layer-2 B-frags (4 KB, L2-resident)
    short8 b2f[4];
#pragma unroll
    for (int kc2 = 0; kc2 < 4; ++kc2)
        b2f[kc2] = *(const short8*)(Wp2e + (kc2 * 64 + fo) * 8);

    auto STAGE = [&](int kc, short* Ad, short* Bd) {
        if (kc < 8) {
#pragma unroll
            for (int p = 0; p < 2; ++p) {
                int s = t + p * 256;
                int b = (s >> 4) & 3;
                int row = ((s >> 6) << 4) + (s & 15);
                const short* gsrc =
                    hb + (size_t)suv[(kc >= 4) * 128 + row] * 128 + (kc & 3) * 32 + b * 8;
                gload_lds16(gsrc, Ad + s * 8);
            }
        } else {
            const float* er = ef + (size_t)(eb + srow) * 64 + (kc - 8) * 32;
#pragma unroll
            for (int p = 0; p < 2; ++p) {
                int b = sb0 + p;
                float4 f0 = *(const float4*)(er + b * 8);
                float4 f1 = *(const float4*)(er + b * 8 + 4);
                short8 v8;
                v8[0] = f2bf(f0.x); v8[1] = f2bf(f0.y);
                v8[2] = f2bf(f0.z); v8[3] = f2bf(f0.w);
                v8[4] = f2bf(f1.x); v8[5] = f2bf(f1.y);
                v8[6] = f2bf(f1.z); v8[7] = f2bf(f1.w);
                *(short8*)(Ad + (sslotbase + b * 16) * 8) = v8;
            }
        }
#pragma unroll
        for (int p = 0; p < 2; ++p) {
            int s = t + p * 256;
            gload_lds16(Wp + (size_t)kc * 4096 + s * 8, Bd + s * 8);
        }
    };

    f32x4 acc[2][8];
#pragma unroll
    for (int i = 0; i < 2; ++i)
#pragma unroll
        for (int j = 0; j < 8; ++j) acc[i][j] = (f32x4){0.f, 0.f, 0.f, 0.f};

    // prologue: 2 stages in flight
    STAGE(0, smem, smem + 4096);
    STAGE(1, smem + 8192, smem + 8192 + 4096);
    for (int kc = 0; kc < 10; ++kc) {
        if (kc < 8)
            asm volatile("s_waitcnt vmcnt(4) lgkmcnt(0)" ::: "memory");
        else if (kc == 8)
            asm volatile("s_waitcnt vmcnt(2) lgkmcnt(0)" ::: "memory");
        else
            asm volatile("s_waitcnt vmcnt(0) lgkmcnt(0)" ::: "memory");
        __builtin_amdgcn_s_barrier();
        __builtin_amdgcn_sched_barrier(0);
        if (kc + 2 < 10) {
            short* An = smem + ((kc + 2) % 3) * 8192;
            STAGE(kc + 2, An, An + 4096);
        }
        short* Ac = smem + (kc % 3) * 8192;
        short* Bc = Ac + 4096;
        short8 afr0 = *(const short8*)(Ac + ((2 * w) * 64 + fo) * 8);
        short8 afr1 = *(const short8*)(Ac + ((2 * w + 1) * 64 + fo) * 8);
#pragma unroll
        for (int cb = 0; cb < 8; ++cb) {
            short8 bfr = *(const short8*)(Bc + (cb * 64 + fo) * 8);
            acc[0][cb] = __builtin_amdgcn_mfma_f32_16x16x32_bf16(afr0, bfr, acc[0][cb], 0, 0, 0);
            acc[1][cb] = __builtin_amdgcn_mfma_f32_16x16x32_bf16(afr1, bfr, acc[1][cb], 0, 0, 0);
        }
    }
    __syncthreads();  // all waves done with staging region before Hid overwrite

    // ---- epilogue 1: bias + relu -> Hid[128][136] bf16 (reuses stage region) ----
    short* Hid = smem;
#pragma unroll
    for (int rb2 = 0; rb2 < 2; ++rb2)
#pragma unroll
        for (int cb = 0; cb < 8; ++cb) {
            int col = cb * 16 + (lane & 15);
            int rbase = 32 * w + rb2 * 16 + ((lane >> 4) << 2);
            float bb = be1s[col];
#pragma unroll
            for (int i = 0; i < 4; ++i)
                Hid[(rbase + i) * 136 + col] = f2bf(fmaxf(acc[rb2][cb][i] + bb, 0.f));
        }
    __syncthreads();

    // ---- layer 2 via MFMA: out[e][0..7] = Hid @ We2p + be2 ----
#pragma unroll
    for (int rf = 0; rf < 2; ++rf) {
        f32x4 a2 = (f32x4){0.f, 0.f, 0.f, 0.f};
        const int rbl = 32 * w + 16 * rf + (lane & 15);
#pragma unroll
        for (int kc2 = 0; kc2 < 4; ++kc2) {
            short8 af = *(const short8*)(Hid + rbl * 136 + kc2 * 32 + 8 * (lane >> 4));
            a2 = __builtin_amdgcn_mfma_f32_16x16x32_bf16(af, b2f[kc2], a2, 0, 0, 0);
        }
        int col = lane & 15;
        if (col < 8) {
            int r0 = eb + 32 * w + 16 * rf + 4 * (lane >> 4);
            float bb = be2[col];
#pragma unroll
            for (int i = 0; i < 4; ++i)
                out[(size_t)(r0 + i) * 8 + col] = a2[i] + bb;
        }
    }
}

// ---------------------------------------------------------------------------
extern "C" void kernel_launch(void* const* d_in, const int* in_sizes, int n_in,
                              void* d_out, int out_size, void* d_ws, size_t ws_size,
                              hipStream_t stream) {
    const float* x   = (const float*)d_in[0];
    const float* ef  = (const float*)d_in[1];
    const float* Ws1 = (const float*)d_in[2];
    const float* Wn1 = (const float*)d_in[3];
    const float* b1  = (const float*)d_in[4];
    const float* g1  = (const float*)d_in[5];
    const float* bt1 = (const float*)d_in[6];
    const float* Ws2 = (const float*)d_in[7];
    const float* Wn2 = (const float*)d_in[8];
    const float* b2  = (const float*)d_in[9];
    const float* g2  = (const float*)d_in[10];
    const float* bt2 = (const float*)d_in[11];
    const float* We1 = (const float*)d_in[12];
    const float* be1 = (const float*)d_in[13];
    const float* We2 = (const float*)d_in[14];
    const float* be2 = (const float*)d_in[15];
    const int* src = (const int*)d_in[16];
    const int* dst = (const int*)d_in[17];
    const int* u   = (const int*)d_in[18];
    const int* v   = (const int*)d_in[19];
    float* out = (float*)d_out;

    // Workspace (~85 MB). z (pre-BN, bf16) lives in d_out's first half
    // (dead before the edge head overwrites d_out). hb aliases xb+agg1b.
    char* p = (char*)d_ws;
    auto take = [&](size_t bytes) {
        char* r = p;
        p += (bytes + 255) & ~(size_t)255;
        return r;
    };
    int* cnt     = (int*)take(NN * 4);       // adjacent to stats: one memset
    float* stats = (float*)take(512 * 4);    // [0:256)=layer1, [256:512)=layer2
    float* invd  = (float*)take(NN * 4);
    int* offs    = (int*)take((NN + 1) * 4);
    int* cursor  = (int*)take(NN * 4);
    int* bsum    = (int*)take(128 * 4);
    int* eidsrc  = (int*)take((size_t)EE * 4);
    short* Wp_e  = (short*)take(320 * 128 * 2);
    short* Wp1   = (short*)take(128 * 128 * 2);
    short* Wp2   = (short*)take(256 * 128 * 2);
    short* Wp2e  = (short*)take(256 * 8 * 2);
    short* xb    = (short*)take((size_t)NN * 64 * 2);
    short* agg1b = (short*)take((size_t)NN * 64 * 2);
    short* h1b   = (short*)take((size_t)NN * 128 * 2);
    short* agg2b = (short*)take((size_t)NN * 128 * 2);
    take(65536);  // pad: node GEMMs read up to ~25 KB past last row
    short* zb = (short*)out;  // bf16 pre-BN z, both layers (25.6 MB of d_out)
    short* hb = xb;           // 25.6 MB union of xb+agg1b

    const int NB = (NN + 1023) / 1024;  // 98 scan blocks

    // ---- CSR build + weight pre-pack + x -> bf16 (one fused kernel) ----
    hipMemsetAsync(cnt, 0, ((char*)stats - (char*)cnt) + 512 * 4, stream);
    k_count<<<(EE + 255) / 256, 256, 0, stream>>>(dst, cnt);
    k_scan_part<<<NB, 1024, 0, stream>>>(cnt, bsum);
    k_scan_base<<<1, 64, 0, stream>>>(bsum, offs, NB);
    k_scan_final<<<NB, 1024, 0, stream>>>(cnt, bsum, offs, cursor, invd);
    k_fill<<<(EE + 255) / 256, 256, 0, stream>>>(src, dst, cursor, eidsrc);
    k_pack_all<<<(92160 + NN * 8 + 255) / 256, 256, 0, stream>>>(
        We1, Ws1, Wn1, Ws2, Wn2, We2, Wp_e, Wp1, Wp2, Wp2e, x, xb);

    // ---- layer 1 (bf16 inputs, fp32 accum/stats; stats fused in GEMM) ----
    k_gather_bf<64><<<(NN * 8 + 255) / 256, 256, 0, stream>>>(xb, offs, eidsrc, invd, agg1b);
    k_node_mfma<2, 2><<<(NN + 127) / 128, 256, 0, stream>>>(xb, agg1b, Wp1, b1, zb, stats);
    k_bnrelu_bf16<<<(NN * 16 + 255) / 256, 256, 0, stream>>>(zb, stats, g1, bt1, h1b);

    // ---- layer 2 ----
    k_gather_bf<128><<<(NN * 16 + 255) / 256, 256, 0, stream>>>(h1b, offs, eidsrc, invd, agg2b);
    k_node_mfma<4, 4><<<(NN + 127) / 128, 256, 0, stream>>>(h1b, agg2b, Wp2, b2, zb, stats + 256);
    k_bnrelu_bf16<<<(NN * 16 + 255) / 256, 256, 0, stream>>>(zb, stats + 256, g2, bt2, hb);

    // ---- edge head (bf16 MFMA, 128-edge tile, counted-vmcnt pipeline) ----
    k_edge_mfma<<<EE / 128, 256, 0, stream>>>(hb, ef, Wp_e, Wp2e, be1, be2, u, v, out);
}